// Round 7
// baseline (398.969 us; speedup 1.0000x reference)
//
#include <hip/hip_runtime.h>
#include <math.h>
#include <stdint.h>

#define D_MODEL 1024
#define NHEADS  16
#define DK      64
#define BATCH   4
#define SEQ     2048
#define MROWS   (BATCH * SEQ)              // 8192
#define TENS    ((size_t)MROWS * D_MODEL)  // 8.39M elems
#define WELT    ((size_t)D_MODEL * D_MODEL)

typedef __attribute__((ext_vector_type(8))) _Float16 f16x8;
typedef __attribute__((ext_vector_type(2))) __fp16 h16x2;
typedef __attribute__((ext_vector_type(4))) float f32x4;
typedef __attribute__((ext_vector_type(8))) unsigned short us8;
typedef __attribute__((ext_vector_type(4))) unsigned short us4;

__device__ __forceinline__ unsigned short f2h(float x) {
    _Float16 h = (_Float16)x;
    return __builtin_bit_cast(unsigned short, h);
}

#if __has_builtin(__builtin_amdgcn_exp2f)
__device__ __forceinline__ float fexp2(float x) { return __builtin_amdgcn_exp2f(x); }
#else
__device__ __forceinline__ float fexp2(float x) { return exp2f(x); }
#endif

// async global->LDS, 16B per lane; LDS dst is wave-uniform base + lane*16
__device__ __forceinline__ void gld_lds16(const void* g, void* l) {
    __builtin_amdgcn_global_load_lds(
        (__attribute__((address_space(1))) void*)(uintptr_t)(g),
        (__attribute__((address_space(3))) void*)(unsigned)(uintptr_t)(l),
        16, 0, 0);
}

// ---------------------------------------------------------------------------
// fp32 -> f16 conversion of the four weight matrices only (Q/K/V conversion
// is fused into proj3's A-staging now). Grid exactly covers 4*WELT.
// ---------------------------------------------------------------------------
__global__ __launch_bounds__(256)
void convert_w_kernel(const float* __restrict__ wq, const float* __restrict__ wk,
                      const float* __restrict__ wv, const float* __restrict__ wo,
                      unsigned short* __restrict__ dst)
{
    size_t i = ((size_t)blockIdx.x * 256 + threadIdx.x) * 4;
    const int widx = (int)(i >> 20);          // WELT == 1<<20
    const float* src = (widx == 0) ? wq : (widx == 1) ? wk : (widx == 2) ? wv : wo;
    const size_t soff = i & (WELT - 1);
    float4 f = *(const float4*)(src + soff);
    us4 o = { f2h(f.x), f2h(f.y), f2h(f.z), f2h(f.w) };
    *(us4*)(dst + i) = o;
}

// XCD-panel decode: flat f in [0,256); XCD slot = f&7 (round-robin dispatch),
// each XCD owns 4 consecutive M-panels; all 8 N-tiles of a panel stay on it.
__device__ __forceinline__ void panel_decode(int f, int& bm, int& bn) {
    const int x = f & 7;
    const int k = f >> 3;                 // 0..31
    const int panel = x * 4 + (k >> 3);   // 32 M-panels of 256 rows
    const int ny = k & 7;                 // 8 N-tiles of 128 cols
    bm = panel * 256;
    bn = ny * 128;
}

// ---------------------------------------------------------------------------
// proj3 GEMM with FUSED fp32->f16 A conversion (removes the Q/K/V convert
// pass entirely). C[M,N] = f16(A32)[M,K] @ B[N,K]^T.
// 256x128 tile, 512 thr = 8 waves, BK=64, 2-deep LDS (96 KB).
// A path (T14 reg-staging): global_load_dwordx4 f32 issued 2 tiles ahead ->
// f2h -> swizzled ds_write_b128. B path: gld_lds16, 1 tile ahead (weights
// are L2-resident, ~200cy). Counted vmcnt(10/8) -- never drained to 0 in
// steady state; fully unrolled so all buffer/regset indices are static.
// ---------------------------------------------------------------------------
__device__ __forceinline__
void gemm_body_cvt(const float* __restrict__ A32,
                   const unsigned short* __restrict__ Bh,
                   void* __restrict__ C, int N, int K, int omode,
                   int bm, int bn,
                   unsigned short* As, unsigned short* Bs)
{
    const int tid  = threadIdx.x;
    const int wave = tid >> 6;
    const int lane = tid & 63;
    const int g    = lane >> 4;
    const int m15  = lane & 15;

    const int srw = lane >> 3;
    const int lc  = (lane & 7) ^ srw;

    const int wr = (wave >> 1) * 64;   // 4 row-waves
    const int wc = (wave & 1) * 64;    // 2 col-waves

    // A-staging assignment: lane handles 4 chunks of one row
    const int arow = tid >> 1;          // 0..255
    const int ac0  = (tid & 1) * 4;     // chunk base 0 or 4

    f32x4 acc[4][4];
#pragma unroll
    for (int i = 0; i < 4; ++i)
#pragma unroll
        for (int j = 0; j < 4; ++j) acc[i][j] = (f32x4){0.f, 0.f, 0.f, 0.f};

    auto loadA = [&](float4* r, int t) {          // 8 dwordx4 f32 per lane
        const float* s = A32 + (size_t)(bm + arow) * K + t * 64 + ac0 * 8;
#pragma unroll
        for (int c = 0; c < 4; ++c) {
            r[2 * c]     = *(const float4*)(s + c * 8);
            r[2 * c + 1] = *(const float4*)(s + c * 8 + 4);
        }
    };
    auto writeA = [&](int buf, const float4* r) {  // 4 swizzled b128 writes
#pragma unroll
        for (int c = 0; c < 4; ++c) {
            us8 o = { f2h(r[2*c].x),   f2h(r[2*c].y),   f2h(r[2*c].z),   f2h(r[2*c].w),
                      f2h(r[2*c+1].x), f2h(r[2*c+1].y), f2h(r[2*c+1].z), f2h(r[2*c+1].w) };
            const int pc = (ac0 + c) ^ (arow & 7);
            *(us8*)&As[buf * (256 * 64) + arow * 64 + pc * 8] = o;
        }
    };
    auto gldB = [&](int buf, int t) {              // 2 gld_lds16 per lane
        const int k0 = t * 64;
#pragma unroll
        for (int j = 0; j < 2; ++j) {
            const int rb = j * 64 + wave * 8;
            gld_lds16(Bh + (size_t)(bn + rb + srw) * K + k0 + lc * 8,
                      &Bs[buf * (128 * 64) + rb * 64]);
        }
    };
    auto compute = [&](int buf) {
        const unsigned short* Ab = &As[buf * (256 * 64)];
        const unsigned short* Bb = &Bs[buf * (128 * 64)];
#pragma unroll
        for (int t = 0; t < 2; ++t) {
            f16x8 af[4], bf[4];
#pragma unroll
            for (int i = 0; i < 4; ++i) {
                int row = wr + i * 16 + m15;
                int pc  = (4 * t + g) ^ (row & 7);
                af[i] = *(const f16x8*)&Ab[row * 64 + pc * 8];
            }
#pragma unroll
            for (int j = 0; j < 4; ++j) {
                int row = wc + j * 16 + m15;
                int pc  = (4 * t + g) ^ (row & 7);
                bf[j] = *(const f16x8*)&Bb[row * 64 + pc * 8];
            }
            __builtin_amdgcn_s_setprio(1);
#pragma unroll
            for (int i = 0; i < 4; ++i)
#pragma unroll
                for (int j = 0; j < 4; ++j)
                    acc[i][j] = __builtin_amdgcn_mfma_f32_16x16x32_f16(
                        af[i], bf[j], acc[i][j], 0, 0, 0);
            __builtin_amdgcn_s_setprio(0);
        }
    };

    const int NT = K / 64;   // 16
    float4 rA0[8], rA1[8];
    // prologue: buf0 = tile0 complete; rA1 = A(1) f32; B(1) in flight.
    loadA(rA0, 0);                                       // vm 8
    gldB(0, 0);                                          // vm 10
    loadA(rA1, 1);                                       // vm 18
    asm volatile("s_waitcnt vmcnt(10)" ::: "memory");    // A(0) arrived
    writeA(0, rA0);
    asm volatile("s_waitcnt vmcnt(8)" ::: "memory");     // B(0) arrived
    asm volatile("s_waitcnt lgkmcnt(0)" ::: "memory");   // A(0) writes visible
    __builtin_amdgcn_s_barrier();
    gldB(1, 1);                                          // vm 10 (A(1)8 + B(1)2)

#pragma unroll
    for (int t = 0; t < NT; ++t) {
        const int cb = t & 1;
        float4* rnext = (t & 1) ? rA1 : rA0;   // freed (held A(t)); reload A(t+2)
        float4* rpend = (t & 1) ? rA0 : rA1;   // holds A(t+1)
        if (t + 2 < NT) loadA(rnext, t + 2);
        if (t + 1 < NT) {
            if (t + 2 < NT) { asm volatile("s_waitcnt vmcnt(10)" ::: "memory"); }
            else            { asm volatile("s_waitcnt vmcnt(2)" ::: "memory"); }
            writeA(cb ^ 1, rpend);             // other buf freed at prior barrier
        }
        __builtin_amdgcn_sched_barrier(0);
        compute(cb);
        __builtin_amdgcn_sched_barrier(0);
        if (t + 1 < NT) {
            if (t + 2 < NT) { asm volatile("s_waitcnt vmcnt(8)" ::: "memory"); }
            else            { asm volatile("s_waitcnt vmcnt(0)" ::: "memory"); }
            asm volatile("s_waitcnt lgkmcnt(0)" ::: "memory");
            __builtin_amdgcn_s_barrier();      // tile t+1 complete; buf cb freed
            if (t + 2 < NT) gldB(cb, t + 2);
        }
    }

#pragma unroll
    for (int i = 0; i < 4; ++i) {
        const int gm0 = bm + wr + i * 16 + g * 4;
#pragma unroll
        for (int j = 0; j < 4; ++j) {
            const int gn = bn + wc + j * 16 + m15;
            if (omode == 1) {
#pragma unroll
                for (int r = 0; r < 4; ++r)
                    ((unsigned short*)C)[(size_t)(gm0 + r) * N + gn] = f2h(acc[i][j][r]);
            } else {
                const int b_ = gm0 >> 11, s_ = gm0 & 2047;
                const int h_ = gn >> 6,  d_ = gn & 63;
                us4 o = { f2h(acc[i][j][0]), f2h(acc[i][j][1]),
                          f2h(acc[i][j][2]), f2h(acc[i][j][3]) };
                // [b][h][s>>3][d][s&7]; s_&7 in {0,4} so the us4 is 8B-aligned
                *(us4*)((unsigned short*)C +
                        (((size_t)(b_ * NHEADS + h_) * 256 + (s_ >> 3)) * 64 + d_) * 8
                        + (s_ & 7)) = o;
            }
        }
    }
}

__global__ __launch_bounds__(512, 2)
void proj3_kernel(const float* __restrict__ Q, const float* __restrict__ K,
                  const float* __restrict__ V,
                  const unsigned short* __restrict__ wq,
                  const unsigned short* __restrict__ wk,
                  const unsigned short* __restrict__ wv,
                  unsigned short* __restrict__ qproj,
                  unsigned short* __restrict__ kproj,
                  unsigned short* __restrict__ vtw)
{
    __shared__ unsigned short As[2 * 256 * 64];   // 64 KB
    __shared__ unsigned short Bs[2 * 128 * 64];   // 32 KB
    const int z = blockIdx.z;
    const float* A = (z == 0) ? Q : (z == 1) ? K : V;
    const unsigned short* B = (z == 0) ? wq : (z == 1) ? wk : wv;
    void* C = (z == 0) ? (void*)qproj : (z == 1) ? (void*)kproj : (void*)vtw;
    int bm, bn;
    panel_decode(blockIdx.x, bm, bn);
    gemm_body_cvt(A, B, C, D_MODEL, D_MODEL, (z == 2) ? 2 : 1, bm, bn, As, Bs);
}

// ---------------------------------------------------------------------------
// gemm_out: f16 NT GEMM, R6 structure unchanged (control): 256x128, 8 waves,
// 3-deep gld_lds pipeline, counted vmcnt(12/6/0), XCD-panel decode.
// ---------------------------------------------------------------------------
__device__ __forceinline__
void gemm_body8(const unsigned short* __restrict__ A,
                const unsigned short* __restrict__ B,
                float* __restrict__ C, int N, int K,
                int bm, int bn,
                unsigned short* As, unsigned short* Bs)
{
    const int tid  = threadIdx.x;
    const int wave = tid >> 6;
    const int lane = tid & 63;
    const int g    = lane >> 4;
    const int m15  = lane & 15;

    const int srw = lane >> 3;
    const int lc  = (lane & 7) ^ srw;

    const int wr = (wave >> 1) * 64;
    const int wc = (wave & 1) * 64;

    f32x4 acc[4][4];
#pragma unroll
    for (int i = 0; i < 4; ++i)
#pragma unroll
        for (int j = 0; j < 4; ++j) acc[i][j] = (f32x4){0.f, 0.f, 0.f, 0.f};

    auto stage = [&](int buf, int t) {
        const int k0 = t * 64;
#pragma unroll
        for (int i = 0; i < 4; ++i) {
            const int rb = i * 64 + wave * 8;
            gld_lds16(A + (size_t)(bm + rb + srw) * K + k0 + lc * 8,
                      &As[buf * (256 * 64) + rb * 64]);
        }
#pragma unroll
        for (int j = 0; j < 2; ++j) {
            const int rb = j * 64 + wave * 8;
            gld_lds16(B + (size_t)(bn + rb + srw) * K + k0 + lc * 8,
                      &Bs[buf * (128 * 64) + rb * 64]);
        }
    };

    auto compute = [&](int buf) {
        const unsigned short* Ab = &As[buf * (256 * 64)];
        const unsigned short* Bb = &Bs[buf * (128 * 64)];
#pragma unroll
        for (int t = 0; t < 2; ++t) {
            f16x8 af[4], bf[4];
#pragma unroll
            for (int i = 0; i < 4; ++i) {
                int row = wr + i * 16 + m15;
                int pc  = (4 * t + g) ^ (row & 7);
                af[i] = *(const f16x8*)&Ab[row * 64 + pc * 8];
            }
#pragma unroll
            for (int j = 0; j < 4; ++j) {
                int row = wc + j * 16 + m15;
                int pc  = (4 * t + g) ^ (row & 7);
                bf[j] = *(const f16x8*)&Bb[row * 64 + pc * 8];
            }
            __builtin_amdgcn_s_setprio(1);
#pragma unroll
            for (int i = 0; i < 4; ++i)
#pragma unroll
                for (int j = 0; j < 4; ++j)
                    acc[i][j] = __builtin_amdgcn_mfma_f32_16x16x32_f16(
                        af[i], bf[j], acc[i][j], 0, 0, 0);
            __builtin_amdgcn_s_setprio(0);
        }
    };

    const int NT = K / 64;   // 16
    stage(0, 0);
    stage(1, 1);
    int cur = 0;
    for (int t = 0; t < NT; ++t) {
        if (t + 2 < NT) {
            int nb = cur + 2; if (nb >= 3) nb -= 3;
            stage(nb, t + 2);
            asm volatile("s_waitcnt vmcnt(12)" ::: "memory");
        } else if (t + 1 < NT) {
            asm volatile("s_waitcnt vmcnt(6)" ::: "memory");
        } else {
            asm volatile("s_waitcnt vmcnt(0)" ::: "memory");
        }
        __builtin_amdgcn_s_barrier();
        __builtin_amdgcn_sched_barrier(0);
        compute(cur);
        __builtin_amdgcn_sched_barrier(0);
        __builtin_amdgcn_s_barrier();
        ++cur; if (cur == 3) cur = 0;
    }

#pragma unroll
    for (int i = 0; i < 4; ++i) {
        const int gm0 = bm + wr + i * 16 + g * 4;
#pragma unroll
        for (int j = 0; j < 4; ++j) {
            const int gn = bn + wc + j * 16 + m15;
#pragma unroll
            for (int r = 0; r < 4; ++r)
                C[(size_t)(gm0 + r) * N + gn] = acc[i][j][r];
        }
    }
}

__global__ __launch_bounds__(512)
void gemm_out_kernel(const unsigned short* __restrict__ A,
                     const unsigned short* __restrict__ B,
                     float* __restrict__ C)
{
    __shared__ unsigned short As[3 * 256 * 64];
    __shared__ unsigned short Bs[3 * 128 * 64];
    int bm, bn;
    panel_decode(blockIdx.x, bm, bn);
    gemm_body8(A, B, C, D_MODEL, D_MODEL, bm, bn, As, Bs);
}

// ---------------------------------------------------------------------------
// Flash attention, transposed-score form, 64 q/wave (mi=4), 2-phase pipeline.
// XCD-grouped flat grid 512 (8 q-blocks per (b,h) on one XCD -> K/V L2 hits).
// CHANGE vs R6: Ps widened to 64 rows/wave (32 KB) so the P round-trip is
// BATCHED -- all 4 mi written, then all read, then denominators -- one lgkm
// dependency point per tile instead of 4 serialized write->read->MFMA chains.
// Same chunk-XOR swizzle (conflict-free, verified R6). defer-max (T13) kept.
// ---------------------------------------------------------------------------
__global__ __launch_bounds__(256, 2)
void attn_kernel(const unsigned short* __restrict__ qp,
                 const unsigned short* __restrict__ kp,
                 const unsigned short* __restrict__ vt,
                 unsigned short* __restrict__ ao)
{
    __shared__ unsigned short Ks[2][64 * 64];   // [buf][key][d], XOR-swizzled
    __shared__ unsigned short VTs[2][64 * 64];  // [buf][d][key], XOR-swizzled
    __shared__ unsigned short Ps[4][64 * 64];   // per-wave P^T, chunk-XOR swizzled

    const int tid = threadIdx.x;
    const int w = tid >> 6, lane = tid & 63;
    const int g = lane >> 4, m15 = lane & 15;

    // XCD-grouped decode: 64 (b,h) pairs, 8 per XCD; 8 q-tiles per pair.
    const int f = blockIdx.x;
    const int bh = (f & 7) * 8 + ((f >> 3) >> 3);   // 0..63
    const int qt = (f >> 3) & 7;
    const int b = bh >> 4, h = bh & 15;

    const int q0 = qt * 256 + w * 64;
    const size_t rowbase = (size_t)b * SEQ;

    const int srw = lane >> 3;
    const int lc  = (lane & 7) ^ srw;

    // Q fragments (B-operand), pre-scaled by (1/sqrt(dk)) * log2(e)
    const _Float16 qscale = (_Float16)(0.125f * 1.4426950408889634f);
    f16x8 qf[4][2];
#pragma unroll
    for (int mi = 0; mi < 4; ++mi)
#pragma unroll
        for (int t = 0; t < 2; ++t) {
            f16x8 v = *(const f16x8*)(qp + (rowbase + q0 + mi * 16 + m15) * D_MODEL
                                      + h * DK + t * 32 + g * 8);
            qf[mi][t] = v * qscale;
        }

    const _Float16 one16 = (_Float16)1.f;
    const f16x8 onesf = { one16, one16, one16, one16, one16, one16, one16, one16 };

    float mrun[4] = {-INFINITY, -INFINITY, -INFINITY, -INFINITY};
    float lrun[4] = {0.f, 0.f, 0.f, 0.f};

    f32x4 accO[4][4];
#pragma unroll
    for (int mi = 0; mi < 4; ++mi)
#pragma unroll
        for (int i = 0; i < 4; ++i) accO[mi][i] = (f32x4){0.f, 0.f, 0.f, 0.f};

    const unsigned short* kbase = kp + rowbase * D_MODEL + h * DK;
    const unsigned short* vbase = vt + (size_t)(b * NHEADS + h) * DK * SEQ;

    auto stage = [&](int buf, int t) {
#pragma unroll
        for (int it = 0; it < 2; ++it) {
            const int rb = w * 16 + it * 8;
            gld_lds16(kbase + (size_t)(t * 64 + rb + srw) * D_MODEL + lc * 8,
                      &Ks[buf][rb * 64]);
            // vt granule layout: elem = (s8*64 + d)*8 + (s&7); 16B = 8 s for one d
            gld_lds16(vbase + ((size_t)(t * 8 + lc) * 64 + rb + srw) * 8,
                      &VTs[buf][rb * 64]);
        }
    };

    const int NT = SEQ / 64;
    stage(0, 0);
    __syncthreads();   // compiler-emitted vmcnt(0) drains prologue loads

    for (int kt = 0; kt < NT; ++kt) {
        const int cur = kt & 1;
        if (kt + 1 < NT) stage(cur ^ 1, kt + 1);   // prefetch overlaps compute below

        // S^T (log2 domain): ST[km][mi] reg r: key=km*16+g*4+r, q=mi*16+m15
        f32x4 ST[4][4];
        __builtin_amdgcn_s_setprio(1);
#pragma unroll
        for (int km = 0; km < 4; ++km) {
            const int row = km * 16 + m15;
            f16x8 kf0 = *(const f16x8*)&Ks[cur][row * 64 + ((0 + g) ^ (row & 7)) * 8];
            f16x8 kf1 = *(const f16x8*)&Ks[cur][row * 64 + ((4 + g) ^ (row & 7)) * 8];
#pragma unroll
            for (int mi = 0; mi < 4; ++mi) {
                f32x4 z = (f32x4){0.f, 0.f, 0.f, 0.f};
                z = __builtin_amdgcn_mfma_f32_16x16x32_f16(kf0, qf[mi][0], z, 0, 0, 0);
                z = __builtin_amdgcn_mfma_f32_16x16x32_f16(kf1, qf[mi][1], z, 0, 0, 0);
                ST[km][mi] = z;
            }
        }
        __builtin_amdgcn_s_setprio(0);

        // local (per-lane) max trees, v_max3-fusable
        float lmx[4];
#pragma unroll
        for (int mi = 0; mi < 4; ++mi) {
            float t0 = fmaxf(fmaxf(ST[0][mi][0], ST[0][mi][1]), ST[0][mi][2]);
            float t1 = fmaxf(fmaxf(ST[0][mi][3], ST[1][mi][0]), ST[1][mi][1]);
            float t2 = fmaxf(fmaxf(ST[1][mi][2], ST[1][mi][3]), ST[2][mi][0]);
            float t3 = fmaxf(fmaxf(ST[2][mi][1], ST[2][mi][2]), ST[2][mi][3]);
            float t4 = fmaxf(fmaxf(ST[3][mi][0], ST[3][mi][1]), ST[3][mi][2]);
            float u0 = fmaxf(fmaxf(t0, t1), t2);
            float u1 = fmaxf(fmaxf(t3, t4), ST[3][mi][3]);
            lmx[mi] = fmaxf(u0, u1);
        }

        // defer-max (T13): reduce+rescale only when some lane exceeds mrun+8
        const float THR = 8.f;
        int need = (lmx[0] > mrun[0] + THR) | (lmx[1] > mrun[1] + THR) |
                   (lmx[2] > mrun[2] + THR) | (lmx[3] > mrun[3] + THR);
        if (__any(need)) {
#pragma unroll
            for (int mi = 0; mi < 4; ++mi) {
                float mx = fmaxf(lmx[mi], __shfl_xor(lmx[mi], 16));
                mx = fmaxf(mx, __shfl_xor(mx, 32));
                float mnew = fmaxf(mrun[mi], mx);
                float scl = fexp2(mrun[mi] - mnew);
                mrun[mi] = mnew;
                lrun[mi] *= scl;
#pragma unroll
                for (int i = 0; i < 4; ++i) accO[mi][i] *= scl;
            }
        }

        // phase 1: P = 2^(S - mrun) for ALL mi -> batched swizzled writes
#pragma unroll
        for (int mi = 0; mi < 4; ++mi) {
            const float mnew = mrun[mi];
            const int prow = mi * 16 + m15;
#pragma unroll
            for (int km = 0; km < 4; ++km) {
                float p0 = fexp2(ST[km][mi][0] - mnew);
                float p1 = fexp2(ST[km][mi][1] - mnew);
                float p2 = fexp2(ST[km][mi][2] - mnew);
                float p3 = fexp2(ST[km][mi][3] - mnew);
                h16x2 d0 = __builtin_amdgcn_cvt_pkrtz(p0, p1);
                h16x2 d1 = __builtin_amdgcn_cvt_pkrtz(p2, p3);
                uint2 wv = { __builtin_bit_cast(unsigned, d0),
                             __builtin_bit_cast(unsigned, d1) };
                // logical chunk = km*2 + (g>>1), half = g&1; phys = chunk^(m15&7)
                const int pc = (km * 2 + (g >> 1)) ^ (m15 & 7);
                *(uint2*)&Ps[w][prow * 64 + pc * 8 + (g & 1) * 4] = wv;
            }
        }
        // phase 2: batched reads (one lgkm dependency point; per-wave FIFO)
        f16x8 pf[4][2];
#pragma unroll
        for (int mi = 0; mi < 4; ++mi) {
            const int prow = mi * 16 + m15;
            pf[mi][0] = *(const f16x8*)&Ps[w][prow * 64 + ((0 + g) ^ (m15 & 7)) * 8];
            pf[mi][1] = *(const f16x8*)&Ps[w][prow * 64 + ((4 + g) ^ (m15 & 7)) * 8];
        }
        // phase 3: denominators on the matrix pipe (independent accumulators)
#pragma unroll
        for (int mi = 0; mi < 4; ++mi) {
            f32x4 zs = (f32x4){0.f, 0.f, 0.f, 0.f};
            zs = __builtin_amdgcn_mfma_f32_16x16x32_f16(onesf, pf[mi][0], zs, 0, 0, 0);
            zs = __builtin_amdgcn_mfma_f32_16x16x32_f16(onesf, pf[mi][1], zs, 0, 0, 0);
            lrun[mi] += zs[0];
        }

        // O^T += V^T·P^T (k32)
        __builtin_amdgcn_s_setprio(1);
#pragma unroll
        for (int i = 0; i < 4; ++i) {
            const int row = i * 16 + m15;
            f16x8 vf0 = *(const f16x8*)&VTs[cur][row * 64 + ((0 + g) ^ (row & 7)) * 8];
            f16x8 vf1 = *(const f16x8*)&VTs[cur][row * 64 + ((4 + g) ^ (row & 7)) * 8];
#pragma unroll
            for (int mi = 0; mi < 4; ++mi) {
                f32x4 a = accO[mi][i];
                a = __builtin_amdgcn_mfma_f32_16x16x32_f16(vf0, pf[mi][0], a, 0, 0, 0);
                a = __builtin_amdgcn_mfma_f32_16x16x32_f16(vf1, pf[mi][1], a, 0, 0, 0);
                accO[mi][i] = a;
            }
        }
        __builtin_amdgcn_s_setprio(0);

        __syncthreads();   // drains vmcnt(0) (prefetch done) + protects buffer reuse
    }

    // epilogue: O^T row d=i*16+g*4+r, col q=mi*16+m15 -> ao[b][s][h*64+d]
#pragma unroll
    for (int mi = 0; mi < 4; ++mi) {
        const float li = 1.f / lrun[mi];
        const size_t qg = rowbase + q0 + mi * 16 + m15;
#pragma unroll
        for (int i = 0; i < 4; ++i) {
            us4 o = { f2h(accO[mi][i][0] * li), f2h(accO[mi][i][1] * li),
                      f2h(accO[mi][i][2] * li), f2h(accO[mi][i][3] * li) };
            *(us4*)(ao + qg * D_MODEL + h * DK + i * 16 + g * 4) = o;
        }
    }
}

// ---------------------------------------------------------------------------
extern "C" void kernel_launch(void* const* d_in, const int* in_sizes, int n_in,
                              void* d_out, int out_size, void* d_ws, size_t ws_size,
                              hipStream_t stream)
{
    const float* Q  = (const float*)d_in[0];
    const float* K  = (const float*)d_in[1];
    const float* V  = (const float*)d_in[2];
    const float* Wq = (const float*)d_in[3];
    const float* Wk = (const float*)d_in[4];
    const float* Wv = (const float*)d_in[5];
    const float* Wo = (const float*)d_in[6];

    unsigned short* base = (unsigned short*)d_ws;
    unsigned short* wq = base;
    unsigned short* wk = wq + WELT;
    unsigned short* wv = wk + WELT;
    unsigned short* wo = wv + WELT;
    unsigned short* qproj = wo + WELT;
    unsigned short* kproj = qproj + TENS;
    unsigned short* vtw   = kproj + TENS;    // [B,H,S/8,DK,8] granule-interleaved
    unsigned short* aow   = vtw + TENS;

    convert_w_kernel<<<dim3(4 * WELT / 1024), 256, 0, stream>>>(Wq, Wk, Wv, Wo, wq);

    proj3_kernel<<<dim3(256, 1, 3), 512, 0, stream>>>(
        Q, K, V, wq, wk, wv, qproj, kproj, vtw);

    attn_kernel<<<dim3(512, 1, 1), 256, 0, stream>>>(
        qproj, kproj, vtw, aow);

    gemm_out_kernel<<<dim3(256, 1, 1), 512, 0, stream>>>(
        aow, wo, (float*)d_out);
}